// Round 8
// baseline (333.545 us; speedup 1.0000x reference)
//
#include <hip/hip_runtime.h>
#include <hip/hip_bf16.h>

// Problem constants (B=1)
#define SEQ   2048
#define HID   2048
#define NH    16
#define NKV   2
#define DH    128
#define QKVN  2560                       // 2048 (Q) + 256 (K) + 256 (V)
#define SCALE 0.08838834764831845f      // 1/sqrt(128)
#define LOG2E 1.4426950408889634f

typedef short bf16x8 __attribute__((ext_vector_type(8)));
typedef short bf16x4 __attribute__((ext_vector_type(4)));
typedef float f32x4  __attribute__((ext_vector_type(4)));

__device__ __forceinline__ short f2bf(float x) {
    unsigned u = __float_as_uint(x);
    u += 0x7FFF + ((u >> 16) & 1);          // round-to-nearest-even
    return (short)(u >> 16);
}

__device__ __forceinline__ void gl2lds16(const short* g, short* l) {
    __builtin_amdgcn_global_load_lds(
        (const __attribute__((address_space(1))) int*)g,
        (__attribute__((address_space(3))) int*)l, 16, 0, 0);
}

// ---------------------------------------------------------------------------
// All four weight transposes in one launch. fp32 [K][N] -> bf16 [N][K].
// ---------------------------------------------------------------------------
__global__ void transp_all(const float* __restrict__ Wq,
                           const float* __restrict__ Wk,
                           const float* __restrict__ Wv,
                           const float* __restrict__ Wo,
                           short* __restrict__ btq,   // [2560][2048]
                           short* __restrict__ wot)   // [2048][2048]
{
    __shared__ short t[32][33];
    const int tb = blockIdx.x;
    const float* src; short* dst; int N, bx, by;
    if (tb < 4096)      { src = Wq; dst = btq;                        N = 2048; int u = tb;        bx = (u & 63) * 32; by = (u >> 6) * 32; }
    else if (tb < 4608) { src = Wk; dst = btq + (size_t)2048 * HID;   N = 256;  int u = tb - 4096; bx = (u & 7) * 32;  by = (u >> 3) * 32; }
    else if (tb < 5120) { src = Wv; dst = btq + (size_t)2304 * HID;   N = 256;  int u = tb - 4608; bx = (u & 7) * 32;  by = (u >> 3) * 32; }
    else                { src = Wo; dst = wot;                        N = 2048; int u = tb - 5120; bx = (u & 63) * 32; by = (u >> 6) * 32; }
    const int K = HID;
    int lx = threadIdx.x, ly = threadIdx.y;
#pragma unroll
    for (int i = 0; i < 4; ++i)
        t[ly + i * 8][lx] = f2bf(src[(size_t)(by + ly + i * 8) * N + bx + lx]);
    __syncthreads();
#pragma unroll
    for (int i = 0; i < 4; ++i)
        dst[(size_t)(bx + ly + i * 8) * K + by + lx] = t[lx][ly + i * 8];
}

// ---------------------------------------------------------------------------
// QKV GEMM, split-K=2 (blockIdx.z): C[M,2560] += A_f32[M,Khalf] @ Bt^T.
// fp32 atomicAdd into zeroed C; bias applied later in rope_cvt.
// ---------------------------------------------------------------------------
__global__ __launch_bounds__(256) void gemm_qkv(const float* __restrict__ A,
                                                const short* __restrict__ Bt,
                                                float* __restrict__ C)
{
    const int K = HID, N = QKVN;
    __shared__ short As[128 * 32];
    __shared__ short Bs[128 * 32];

    const int tid  = threadIdx.x;
    const int wave = tid >> 6;
    const int lane = tid & 63;
    const int quad = lane >> 4;
    const int l16  = lane & 15;
    const int m0 = blockIdx.y * 128;
    const int n0 = blockIdx.x * 128;
    const int kb0 = blockIdx.z * (K / 2);
    const int wm = (wave >> 1) * 64;
    const int wn = (wave & 1) * 64;

    const int r0 = tid >> 2;
    const int c0 = (tid & 3) * 8;
    const float* gA = A + (size_t)(m0 + r0) * K + c0;
    const short* gB = Bt + (size_t)(n0 + r0) * K + c0;
    short* lB = Bs + wave * 512;

    f32x4 acc[4][4];
#pragma unroll
    for (int i = 0; i < 4; ++i)
#pragma unroll
        for (int j = 0; j < 4; ++j) acc[i][j] = (f32x4){0.f, 0.f, 0.f, 0.f};

    for (int k0 = kb0; k0 < kb0 + K / 2; k0 += 32) {
        __syncthreads();
        gl2lds16(gB + k0,                  lB);
        gl2lds16(gB + k0 + (size_t)64 * K, lB + 2048);
        float4 f0 = *(const float4*)(gA + k0);
        float4 f1 = *(const float4*)(gA + k0 + 4);
        float4 f2 = *(const float4*)(gA + k0 + (size_t)64 * K);
        float4 f3 = *(const float4*)(gA + k0 + (size_t)64 * K + 4);
        bf16x8 a0 = { f2bf(f0.x), f2bf(f0.y), f2bf(f0.z), f2bf(f0.w),
                      f2bf(f1.x), f2bf(f1.y), f2bf(f1.z), f2bf(f1.w) };
        bf16x8 a1 = { f2bf(f2.x), f2bf(f2.y), f2bf(f2.z), f2bf(f2.w),
                      f2bf(f3.x), f2bf(f3.y), f2bf(f3.z), f2bf(f3.w) };
        *(bf16x8*)&As[r0 * 32 + c0]        = a0;
        *(bf16x8*)&As[(r0 + 64) * 32 + c0] = a1;
        __syncthreads();

        bf16x8 av[4], bv4[4];
#pragma unroll
        for (int mt = 0; mt < 4; ++mt)
            av[mt] = *(const bf16x8*)&As[(wm + mt * 16 + l16) * 32 + quad * 8];
#pragma unroll
        for (int nt = 0; nt < 4; ++nt)
            bv4[nt] = *(const bf16x8*)&Bs[(wn + nt * 16 + l16) * 32 + quad * 8];
#pragma unroll
        for (int mt = 0; mt < 4; ++mt)
#pragma unroll
            for (int nt = 0; nt < 4; ++nt)
                acc[mt][nt] = __builtin_amdgcn_mfma_f32_16x16x32_bf16(
                    av[mt], bv4[nt], acc[mt][nt], 0, 0, 0);
    }

#pragma unroll
    for (int nt = 0; nt < 4; ++nt) {
        int col = n0 + wn + nt * 16 + l16;
#pragma unroll
        for (int mt = 0; mt < 4; ++mt)
#pragma unroll
            for (int r = 0; r < 4; ++r) {
                int row = m0 + wm + mt * 16 + quad * 4 + r;
                atomicAdd(&C[(size_t)row * N + col], acc[mt][nt][r]);
            }
    }
}

// ---------------------------------------------------------------------------
// Wo GEMM, split-K=2: out += ctx_bf16 @ wot^T, fp32 atomicAdd into zeroed out.
// ---------------------------------------------------------------------------
__global__ __launch_bounds__(256) void gemm_wo(const short* __restrict__ A,
                                               const short* __restrict__ Bt,
                                               float* __restrict__ C)
{
    const int K = HID, N = HID;
    __shared__ short As[128 * 32];
    __shared__ short Bs[128 * 32];

    const int tid  = threadIdx.x;
    const int wave = tid >> 6;
    const int lane = tid & 63;
    const int quad = lane >> 4;
    const int l16  = lane & 15;
    const int m0 = blockIdx.y * 128;
    const int n0 = blockIdx.x * 128;
    const int kb0 = blockIdx.z * (K / 2);
    const int wm = (wave >> 1) * 64;
    const int wn = (wave & 1) * 64;

    const int r0 = tid >> 2;
    const int c0 = (tid & 3) * 8;
    const short* gA = A  + (size_t)(m0 + r0) * K + c0;
    const short* gB = Bt + (size_t)(n0 + r0) * K + c0;
    short* lA = As + wave * 512;
    short* lB = Bs + wave * 512;

    f32x4 acc[4][4];
#pragma unroll
    for (int i = 0; i < 4; ++i)
#pragma unroll
        for (int j = 0; j < 4; ++j) acc[i][j] = (f32x4){0.f, 0.f, 0.f, 0.f};

    for (int k0 = kb0; k0 < kb0 + K / 2; k0 += 32) {
        __syncthreads();
        gl2lds16(gA + k0,                  lA);
        gl2lds16(gA + k0 + (size_t)64 * K, lA + 2048);
        gl2lds16(gB + k0,                  lB);
        gl2lds16(gB + k0 + (size_t)64 * K, lB + 2048);
        __syncthreads();

        bf16x8 av[4], bv[4];
#pragma unroll
        for (int mt = 0; mt < 4; ++mt)
            av[mt] = *(const bf16x8*)&As[(wm + mt * 16 + l16) * 32 + quad * 8];
#pragma unroll
        for (int nt = 0; nt < 4; ++nt)
            bv[nt] = *(const bf16x8*)&Bs[(wn + nt * 16 + l16) * 32 + quad * 8];
#pragma unroll
        for (int mt = 0; mt < 4; ++mt)
#pragma unroll
            for (int nt = 0; nt < 4; ++nt)
                acc[mt][nt] = __builtin_amdgcn_mfma_f32_16x16x32_bf16(
                    av[mt], bv[nt], acc[mt][nt], 0, 0, 0);
    }

#pragma unroll
    for (int mt = 0; mt < 4; ++mt)
#pragma unroll
        for (int nt = 0; nt < 4; ++nt) {
            int col = n0 + wn + nt * 16 + l16;
#pragma unroll
            for (int r = 0; r < 4; ++r) {
                int row = m0 + wm + mt * 16 + quad * 4 + r;
                atomicAdd(&C[(size_t)row * N + col], acc[mt][nt][r]);
            }
        }
}

// ---------------------------------------------------------------------------
// Fused bias + RoPE + layout pass. Q: +bq, rope, in-place fp32.
// K: +bk, rope -> bf16 kbf. V: +bv -> bf16 transposed vtb.
// ---------------------------------------------------------------------------
__global__ void rope_cvt(float* __restrict__ qkv,
                         const float* __restrict__ cosp,
                         const float* __restrict__ sinp,
                         const float* __restrict__ bq,
                         const float* __restrict__ bk,
                         const float* __restrict__ bv,
                         short* __restrict__ kb,
                         short* __restrict__ vt)
{
    int g = blockIdx.x * 256 + threadIdx.x;
    if (g < SEQ * NH * 64) {                        // Q: bias + RoPE in-place
        int d = g & 63;
        int h = (g >> 6) & (NH - 1);
        int s = g >> 10;
        float* base = qkv + (size_t)s * QKVN + h * DH;
        float x0 = base[d]      + bq[h * DH + d];
        float x1 = base[d + 64] + bq[h * DH + d + 64];
        float c0 = cosp[s * DH + d],  c1 = cosp[s * DH + d + 64];
        float s0 = sinp[s * DH + d],  s1 = sinp[s * DH + d + 64];
        base[d]      = x0 * c0 - x1 * s0;
        base[d + 64] = x1 * c1 + x0 * s1;
        return;
    }
    g -= SEQ * NH * 64;
    if (g < SEQ * NKV * 64) {                       // K: bias + RoPE -> bf16
        int d   = g & 63;
        int kvh = (g >> 6) & (NKV - 1);
        int s   = g >> 7;
        const float* base = qkv + (size_t)s * QKVN + NH * DH + kvh * DH;
        float x0 = base[d]      + bk[kvh * DH + d];
        float x1 = base[d + 64] + bk[kvh * DH + d + 64];
        float c0 = cosp[s * DH + d],  c1 = cosp[s * DH + d + 64];
        float s0 = sinp[s * DH + d],  s1 = sinp[s * DH + d + 64];
        short* ob = kb + (size_t)s * (NKV * DH) + kvh * DH;
        ob[d]      = f2bf(x0 * c0 - x1 * s0);
        ob[d + 64] = f2bf(x1 * c1 + x0 * s1);
        return;
    }
    g -= SEQ * NKV * 64;                            // V: bias -> bf16 transposed
    int s   = g & (SEQ - 1);
    int d   = (g >> 11) & (DH - 1);
    int kvh = g >> 18;
    vt[g] = f2bf(qkv[(size_t)s * QKVN + NH * DH + NKV * DH + kvh * DH + d]
                 + bv[kvh * DH + d]);
}

// ---------------------------------------------------------------------------
// MFMA flash attention (R7, known-good): transposed scores, 32-key tiles,
// SL*log2e folded into Q fragment, ballot-guarded O rescale.
// ---------------------------------------------------------------------------
__global__ __launch_bounds__(256) void attn_mfma(const float* __restrict__ Qp,
                                                 const short* __restrict__ Kb,
                                                 const short* __restrict__ Vtb,
                                                 short* __restrict__ ctx)
{
    __shared__ short Ks[32][136];
    __shared__ short Vs[128][40];
    __shared__ short Ps[4][16][40];    // per-wave [q][k] operand layout

    const int bid = blockIdx.x;
    const int h   = bid & 15;
    const int qb  = 31 - (bid >> 4);   // heavy q-blocks dispatch first
    const int kvh = h >> 3;
    const int tid  = threadIdx.x;
    const int wave = tid >> 6;
    const int lane = tid & 63;
    const int quad = lane >> 4;
    const int l16  = lane & 15;

    const int qrow0 = qb * 64 + wave * 16;
    const int qg    = qrow0 + l16;       // this lane's q column

    const float SL = SCALE * LOG2E;
    bf16x8 aq[4];
    {
        const float* qsrc = Qp + (size_t)(qrow0 + l16) * QKVN + h * DH + quad * 8;
#pragma unroll
        for (int c = 0; c < 4; ++c) {
            float4 f0 = *(const float4*)(qsrc + c * 32);
            float4 f1 = *(const float4*)(qsrc + c * 32 + 4);
            bf16x8 a;
            a[0] = f2bf(f0.x * SL); a[1] = f2bf(f0.y * SL);
            a[2] = f2bf(f0.z * SL); a[3] = f2bf(f0.w * SL);
            a[4] = f2bf(f1.x * SL); a[5] = f2bf(f1.y * SL);
            a[6] = f2bf(f1.z * SL); a[7] = f2bf(f1.w * SL);
            aq[c] = a;
        }
    }

    f32x4 of[8];
#pragma unroll
    for (int t = 0; t < 8; ++t) of[t] = (f32x4){0.f, 0.f, 0.f, 0.f};
    float m_old = -1e30f, l_sum = 0.f;

    const int nkt = (qb + 1) * 2;

    for (int kt = 0; kt < nkt; ++kt) {
        const int kbase = kt * 32;
        __syncthreads();
        {
#pragma unroll
            for (int i = 0; i < 2; ++i) {
                int cid = tid + i * 256;
                int r = cid >> 4, c = (cid & 15) * 8;
                *(int4*)&Ks[r][c] =
                    *(const int4*)(Kb + (size_t)(kbase + r) * (NKV * DH) + kvh * DH + c);
            }
        }
        {
#pragma unroll
            for (int i = 0; i < 2; ++i) {
                int cid = tid + i * 256;
                int d = cid >> 2, c = (cid & 3) * 8;
                *(int4*)&Vs[d][c] =
                    *(const int4*)(Vtb + (size_t)kvh * DH * SEQ + (size_t)d * SEQ + kbase + c);
            }
        }
        __syncthreads();

        if (kbase > qrow0 + 15) continue;

        f32x4 s0 = (f32x4){0.f, 0.f, 0.f, 0.f};
        f32x4 s1 = (f32x4){0.f, 0.f, 0.f, 0.f};
#pragma unroll
        for (int c = 0; c < 4; ++c) {
            bf16x8 ak0 = *(const bf16x8*)&Ks[l16][c * 32 + quad * 8];
            bf16x8 ak1 = *(const bf16x8*)&Ks[16 + l16][c * 32 + quad * 8];
            s0 = __builtin_amdgcn_mfma_f32_16x16x32_bf16(ak0, aq[c], s0, 0, 0, 0);
            s1 = __builtin_amdgcn_mfma_f32_16x16x32_bf16(ak1, aq[c], s1, 0, 0, 0);
        }

        float x[8];
#pragma unroll
        for (int r = 0; r < 4; ++r) {
            x[r]     = (kbase + quad * 4 + r      <= qg) ? s0[r] : -1e30f;
            x[4 + r] = (kbase + 16 + quad * 4 + r <= qg) ? s1[r] : -1e30f;
        }
        float mr = x[0];
#pragma unroll
        for (int i = 1; i < 8; ++i) mr = fmaxf(mr, x[i]);
        mr = fmaxf(mr, __shfl_xor(mr, 16));
        mr = fmaxf(mr, __shfl_xor(mr, 32));
        float mn    = fmaxf(m_old, mr);
        float alpha = __builtin_amdgcn_exp2f(m_old - mn);
        float p[8], ps = 0.f;
#pragma unroll
        for (int i = 0; i < 8; ++i) { p[i] = __builtin_amdgcn_exp2f(x[i] - mn); ps += p[i]; }
        ps += __shfl_xor(ps, 16);
        ps += __shfl_xor(ps, 32);
        l_sum = l_sum * alpha + ps;

        bf16x4 w0 = { f2bf(p[0]), f2bf(p[1]), f2bf(p[2]), f2bf(p[3]) };
        bf16x4 w1 = { f2bf(p[4]), f2bf(p[5]), f2bf(p[6]), f2bf(p[7]) };
        *(bf16x4*)&Ps[wave][l16][quad * 4]      = w0;
        *(bf16x4*)&Ps[wave][l16][16 + quad * 4] = w1;

        if (__ballot(mn > m_old)) {
#pragma unroll
            for (int t = 0; t < 8; ++t)
#pragma unroll
                for (int r = 0; r < 4; ++r) of[t][r] *= alpha;
        }
        m_old = mn;

        bf16x8 bp = *(const bf16x8*)&Ps[wave][l16][quad * 8];
#pragma unroll
        for (int t = 0; t < 8; ++t) {
            bf16x8 av = *(const bf16x8*)&Vs[t * 16 + l16][quad * 8];
            of[t] = __builtin_amdgcn_mfma_f32_16x16x32_bf16(av, bp, of[t], 0, 0, 0);
        }
    }

    float inv = 1.f / l_sum;
    short* dst = ctx + (size_t)qg * HID + h * DH + quad * 4;
#pragma unroll
    for (int t = 0; t < 8; ++t) {
        bf16x4 wv = { f2bf(of[t][0] * inv), f2bf(of[t][1] * inv),
                      f2bf(of[t][2] * inv), f2bf(of[t][3] * inv) };
        *(bf16x4*)(dst + t * 16) = wv;
    }
}

// ---------------------------------------------------------------------------
extern "C" void kernel_launch(void* const* d_in, const int* in_sizes, int n_in,
                              void* d_out, int out_size, void* d_ws, size_t ws_size,
                              hipStream_t stream)
{
    const float* hs   = (const float*)d_in[0];
    const float* cosp = (const float*)d_in[1];
    const float* sinp = (const float*)d_in[2];
    const float* Wq = (const float*)d_in[4];
    const float* bq = (const float*)d_in[5];
    const float* Wk = (const float*)d_in[6];
    const float* bk = (const float*)d_in[7];
    const float* Wv = (const float*)d_in[8];
    const float* bv = (const float*)d_in[9];
    const float* Wo = (const float*)d_in[10];
    float* out = (float*)d_out;

    char* w = (char*)d_ws;
    short* btq  = (short*)w;  w += (size_t)QKVN * HID * 2;          // 10 MB
    short* wot  = (short*)w;  w += (size_t)HID * HID * 2;           //  8 MB
    float* qkv  = (float*)w;  w += (size_t)SEQ * QKVN * 4;          // 20 MB
    short* kbf  = (short*)w;  w += (size_t)SEQ * (NKV * DH) * 2;    //  1 MB
    short* vtb  = (short*)w;  w += (size_t)NKV * DH * SEQ * 2;      //  1 MB
    short* ctxb = (short*)w;                                        //  8 MB

    // 0. zero the split-K accumulation targets
    hipMemsetAsync(qkv, 0, (size_t)SEQ * QKVN * 4, stream);
    hipMemsetAsync(out, 0, (size_t)SEQ * HID * 4, stream);

    // 1. all weight transposes (fp32 [K][N] -> bf16 [N][K])
    transp_all<<<9216, dim3(32, 8), 0, stream>>>(Wq, Wk, Wv, Wo, btq, wot);

    // 2. QKV projection, split-K=2, atomic accumulate (bias deferred)
    gemm_qkv<<<dim3(QKVN / 128, SEQ / 128, 2), 256, 0, stream>>>(hs, btq, qkv);

    // 3. bias + RoPE Q/K + V transpose, one launch
    {
        int total = SEQ * NH * 64 + SEQ * NKV * 64 + NKV * DH * SEQ;
        rope_cvt<<<total / 256, 256, 0, stream>>>(qkv, cosp, sinp, bq, bk, bv, kbf, vtb);
    }

    // 4. attention (bf16 ctx out)
    attn_mfma<<<dim3(32 * NH), 256, 0, stream>>>(qkv, kbf, vtb, ctxb);

    // 5. output projection, split-K=2, atomic accumulate into zeroed out
    gemm_wo<<<dim3(HID / 128, SEQ / 128, 2), 256, 0, stream>>>(ctxb, wot, out);
}

// Round 9
// 323.067 us; speedup vs baseline: 1.0324x; 1.0324x over previous
//
#include <hip/hip_runtime.h>
#include <hip/hip_bf16.h>

// Problem constants (B=1)
#define SEQ   2048
#define HID   2048
#define NH    16
#define NKV   2
#define DH    128
#define QKVN  2560                       // 2048 (Q) + 256 (K) + 256 (V)
#define SCALE 0.08838834764831845f      // 1/sqrt(128)
#define LOG2E 1.4426950408889634f

typedef short bf16x8 __attribute__((ext_vector_type(8)));
typedef short bf16x4 __attribute__((ext_vector_type(4)));
typedef float f32x4  __attribute__((ext_vector_type(4)));

__device__ __forceinline__ short f2bf(float x) {
    unsigned u = __float_as_uint(x);
    u += 0x7FFF + ((u >> 16) & 1);          // round-to-nearest-even
    return (short)(u >> 16);
}
__device__ __forceinline__ float bf2f(short s) {
    return __uint_as_float(((unsigned)(unsigned short)s) << 16);
}

__device__ __forceinline__ void gl2lds16(const short* g, short* l) {
    __builtin_amdgcn_global_load_lds(
        (const __attribute__((address_space(1))) int*)g,
        (__attribute__((address_space(3))) int*)l, 16, 0, 0);
}

// ---------------------------------------------------------------------------
// All four weight transposes, vectorized. fp32 [K][N] -> bf16 [N][K].
// 256 threads, 32x32 tile: float4 loads, bf16x4 (8B) stores.
// ---------------------------------------------------------------------------
__global__ void transp_all(const float* __restrict__ Wq,
                           const float* __restrict__ Wk,
                           const float* __restrict__ Wv,
                           const float* __restrict__ Wo,
                           short* __restrict__ btq,   // [2560][2048]
                           short* __restrict__ wot)   // [2048][2048]
{
    __shared__ short t[32][36];            // [col][row], +4 pad
    const int tb = blockIdx.x;
    const float* src; short* dst; int N, bx, by;
    if (tb < 4096)      { src = Wq; dst = btq;                        N = 2048; int u = tb;        bx = (u & 63) * 32; by = (u >> 6) * 32; }
    else if (tb < 4608) { src = Wk; dst = btq + (size_t)2048 * HID;   N = 256;  int u = tb - 4096; bx = (u & 7) * 32;  by = (u >> 3) * 32; }
    else if (tb < 5120) { src = Wv; dst = btq + (size_t)2304 * HID;   N = 256;  int u = tb - 4608; bx = (u & 7) * 32;  by = (u >> 3) * 32; }
    else                { src = Wo; dst = wot;                        N = 2048; int u = tb - 5120; bx = (u & 63) * 32; by = (u >> 6) * 32; }
    const int K = HID;
    const int tid = threadIdx.x;
    {
        int row = tid >> 3, c4 = (tid & 7) * 4;    // src row (k), col group (n)
        float4 v = *(const float4*)(src + (size_t)(by + row) * N + bx + c4);
        t[c4 + 0][row] = f2bf(v.x);
        t[c4 + 1][row] = f2bf(v.y);
        t[c4 + 2][row] = f2bf(v.z);
        t[c4 + 3][row] = f2bf(v.w);
    }
    __syncthreads();
    {
        int nrow = tid >> 3, k4 = (tid & 7) * 4;   // dst row (n), col group (k)
        bf16x4 w = { t[nrow][k4], t[nrow][k4 + 1], t[nrow][k4 + 2], t[nrow][k4 + 3] };
        *(bf16x4*)(dst + (size_t)(bx + nrow) * K + by + k4) = w;
    }
}

// ---------------------------------------------------------------------------
// QKV GEMM, split-K=2 (blockIdx.z): C[M,2560] += A_f32[M,Khalf] @ Bt^T.
// fp32 atomicAdd into zeroed C; bias applied later in rope_cvt.
// ---------------------------------------------------------------------------
__global__ __launch_bounds__(256) void gemm_qkv(const float* __restrict__ A,
                                                const short* __restrict__ Bt,
                                                float* __restrict__ C)
{
    const int K = HID, N = QKVN;
    __shared__ short As[128 * 32];
    __shared__ short Bs[128 * 32];

    const int tid  = threadIdx.x;
    const int wave = tid >> 6;
    const int lane = tid & 63;
    const int quad = lane >> 4;
    const int l16  = lane & 15;
    const int m0 = blockIdx.y * 128;
    const int n0 = blockIdx.x * 128;
    const int kb0 = blockIdx.z * (K / 2);
    const int wm = (wave >> 1) * 64;
    const int wn = (wave & 1) * 64;

    const int r0 = tid >> 2;
    const int c0 = (tid & 3) * 8;
    const float* gA = A + (size_t)(m0 + r0) * K + c0;
    const short* gB = Bt + (size_t)(n0 + r0) * K + c0;
    short* lB = Bs + wave * 512;

    f32x4 acc[4][4];
#pragma unroll
    for (int i = 0; i < 4; ++i)
#pragma unroll
        for (int j = 0; j < 4; ++j) acc[i][j] = (f32x4){0.f, 0.f, 0.f, 0.f};

    for (int k0 = kb0; k0 < kb0 + K / 2; k0 += 32) {
        __syncthreads();
        gl2lds16(gB + k0,                  lB);
        gl2lds16(gB + k0 + (size_t)64 * K, lB + 2048);
        float4 f0 = *(const float4*)(gA + k0);
        float4 f1 = *(const float4*)(gA + k0 + 4);
        float4 f2 = *(const float4*)(gA + k0 + (size_t)64 * K);
        float4 f3 = *(const float4*)(gA + k0 + (size_t)64 * K + 4);
        bf16x8 a0 = { f2bf(f0.x), f2bf(f0.y), f2bf(f0.z), f2bf(f0.w),
                      f2bf(f1.x), f2bf(f1.y), f2bf(f1.z), f2bf(f1.w) };
        bf16x8 a1 = { f2bf(f2.x), f2bf(f2.y), f2bf(f2.z), f2bf(f2.w),
                      f2bf(f3.x), f2bf(f3.y), f2bf(f3.z), f2bf(f3.w) };
        *(bf16x8*)&As[r0 * 32 + c0]        = a0;
        *(bf16x8*)&As[(r0 + 64) * 32 + c0] = a1;
        __syncthreads();

        bf16x8 av[4], bv4[4];
#pragma unroll
        for (int mt = 0; mt < 4; ++mt)
            av[mt] = *(const bf16x8*)&As[(wm + mt * 16 + l16) * 32 + quad * 8];
#pragma unroll
        for (int nt = 0; nt < 4; ++nt)
            bv4[nt] = *(const bf16x8*)&Bs[(wn + nt * 16 + l16) * 32 + quad * 8];
#pragma unroll
        for (int mt = 0; mt < 4; ++mt)
#pragma unroll
            for (int nt = 0; nt < 4; ++nt)
                acc[mt][nt] = __builtin_amdgcn_mfma_f32_16x16x32_bf16(
                    av[mt], bv4[nt], acc[mt][nt], 0, 0, 0);
    }

#pragma unroll
    for (int nt = 0; nt < 4; ++nt) {
        int col = n0 + wn + nt * 16 + l16;
#pragma unroll
        for (int mt = 0; mt < 4; ++mt)
#pragma unroll
            for (int r = 0; r < 4; ++r) {
                int row = m0 + wm + mt * 16 + quad * 4 + r;
                atomicAdd(&C[(size_t)row * N + col], acc[mt][nt][r]);
            }
    }
}

// ---------------------------------------------------------------------------
// Wo GEMM, split-K=2: out += ctx_bf16 @ wot^T, fp32 atomicAdd into zeroed out.
// ---------------------------------------------------------------------------
__global__ __launch_bounds__(256) void gemm_wo(const short* __restrict__ A,
                                               const short* __restrict__ Bt,
                                               float* __restrict__ C)
{
    const int K = HID, N = HID;
    __shared__ short As[128 * 32];
    __shared__ short Bs[128 * 32];

    const int tid  = threadIdx.x;
    const int wave = tid >> 6;
    const int lane = tid & 63;
    const int quad = lane >> 4;
    const int l16  = lane & 15;
    const int m0 = blockIdx.y * 128;
    const int n0 = blockIdx.x * 128;
    const int kb0 = blockIdx.z * (K / 2);
    const int wm = (wave >> 1) * 64;
    const int wn = (wave & 1) * 64;

    const int r0 = tid >> 2;
    const int c0 = (tid & 3) * 8;
    const short* gA = A  + (size_t)(m0 + r0) * K + c0;
    const short* gB = Bt + (size_t)(n0 + r0) * K + c0;
    short* lA = As + wave * 512;
    short* lB = Bs + wave * 512;

    f32x4 acc[4][4];
#pragma unroll
    for (int i = 0; i < 4; ++i)
#pragma unroll
        for (int j = 0; j < 4; ++j) acc[i][j] = (f32x4){0.f, 0.f, 0.f, 0.f};

    for (int k0 = kb0; k0 < kb0 + K / 2; k0 += 32) {
        __syncthreads();
        gl2lds16(gA + k0,                  lA);
        gl2lds16(gA + k0 + (size_t)64 * K, lA + 2048);
        gl2lds16(gB + k0,                  lB);
        gl2lds16(gB + k0 + (size_t)64 * K, lB + 2048);
        __syncthreads();

        bf16x8 av[4], bv[4];
#pragma unroll
        for (int mt = 0; mt < 4; ++mt)
            av[mt] = *(const bf16x8*)&As[(wm + mt * 16 + l16) * 32 + quad * 8];
#pragma unroll
        for (int nt = 0; nt < 4; ++nt)
            bv[nt] = *(const bf16x8*)&Bs[(wn + nt * 16 + l16) * 32 + quad * 8];
#pragma unroll
        for (int mt = 0; mt < 4; ++mt)
#pragma unroll
            for (int nt = 0; nt < 4; ++nt)
                acc[mt][nt] = __builtin_amdgcn_mfma_f32_16x16x32_bf16(
                    av[mt], bv[nt], acc[mt][nt], 0, 0, 0);
    }

#pragma unroll
    for (int mt = 0; mt < 4; ++mt)
#pragma unroll
        for (int nt = 0; nt < 4; ++nt) {
            int col = n0 + wn + nt * 16 + l16;
#pragma unroll
            for (int r = 0; r < 4; ++r) {
                int row = m0 + wm + mt * 16 + quad * 4 + r;
                atomicAdd(&C[(size_t)row * N + col], acc[mt][nt][r]);
            }
        }
}

// ---------------------------------------------------------------------------
// Fused bias + RoPE + layout pass. Q: +bq, rope, in-place fp32.
// K: +bk, rope -> bf16 kbf. V: +bv -> bf16 transposed vtb.
// ---------------------------------------------------------------------------
__global__ void rope_cvt(float* __restrict__ qkv,
                         const float* __restrict__ cosp,
                         const float* __restrict__ sinp,
                         const float* __restrict__ bq,
                         const float* __restrict__ bk,
                         const float* __restrict__ bv,
                         short* __restrict__ kb,
                         short* __restrict__ vt)
{
    int g = blockIdx.x * 256 + threadIdx.x;
    if (g < SEQ * NH * 64) {                        // Q: bias + RoPE in-place
        int d = g & 63;
        int h = (g >> 6) & (NH - 1);
        int s = g >> 10;
        float* base = qkv + (size_t)s * QKVN + h * DH;
        float x0 = base[d]      + bq[h * DH + d];
        float x1 = base[d + 64] + bq[h * DH + d + 64];
        float c0 = cosp[s * DH + d],  c1 = cosp[s * DH + d + 64];
        float s0 = sinp[s * DH + d],  s1 = sinp[s * DH + d + 64];
        base[d]      = x0 * c0 - x1 * s0;
        base[d + 64] = x1 * c1 + x0 * s1;
        return;
    }
    g -= SEQ * NH * 64;
    if (g < SEQ * NKV * 64) {                       // K: bias + RoPE -> bf16
        int d   = g & 63;
        int kvh = (g >> 6) & (NKV - 1);
        int s   = g >> 7;
        const float* base = qkv + (size_t)s * QKVN + NH * DH + kvh * DH;
        float x0 = base[d]      + bk[kvh * DH + d];
        float x1 = base[d + 64] + bk[kvh * DH + d + 64];
        float c0 = cosp[s * DH + d],  c1 = cosp[s * DH + d + 64];
        float s0 = sinp[s * DH + d],  s1 = sinp[s * DH + d + 64];
        short* ob = kb + (size_t)s * (NKV * DH) + kvh * DH;
        ob[d]      = f2bf(x0 * c0 - x1 * s0);
        ob[d + 64] = f2bf(x1 * c1 + x0 * s1);
        return;
    }
    g -= SEQ * NKV * 64;                            // V: bias -> bf16 transposed
    int s   = g & (SEQ - 1);
    int d   = (g >> 11) & (DH - 1);
    int kvh = g >> 18;
    vt[g] = f2bf(qkv[(size_t)s * QKVN + NH * DH + NKV * DH + kvh * DH + d]
                 + bv[kvh * DH + d]);
}

// ---------------------------------------------------------------------------
// MFMA flash attention with key-split for heavy q-blocks.
// bid<512: qb=16..31 split into 2 key-chunks -> partial (O/l, m, l) scratch.
// bid>=512: qb=0..15 full range -> ctx directly.
// ---------------------------------------------------------------------------
__global__ __launch_bounds__(256) void attn_mfma(const float* __restrict__ Qp,
                                                 const short* __restrict__ Kb,
                                                 const short* __restrict__ Vtb,
                                                 short* __restrict__ ctx,
                                                 short* __restrict__ opart,
                                                 float2* __restrict__ mlbuf)
{
    __shared__ short Ks[32][136];
    __shared__ short Vs[128][40];
    __shared__ short Ps[4][16][40];    // per-wave [q][k] operand layout

    const int bid = blockIdx.x;
    int qb, h, kt0, kt1, slot;
    if (bid < 512) {                   // split blocks, heavy qb first
        qb = 31 - (bid >> 5);          // 31..16
        h  = (bid >> 1) & 15;
        int chunk = bid & 1;
        int half  = qb + 1;            // 32-key tiles per chunk
        kt0 = chunk * half;
        kt1 = kt0 + half;
        slot = ((qb - 16) * 16 + h) * 2 + chunk;
    } else {
        int u = bid - 512;
        qb = 15 - (u >> 4);
        h  = u & 15;
        kt0 = 0;
        kt1 = (qb + 1) * 2;
        slot = -1;
    }
    const int kvh = h >> 3;
    const int tid  = threadIdx.x;
    const int wave = tid >> 6;
    const int lane = tid & 63;
    const int quad = lane >> 4;
    const int l16  = lane & 15;

    const int qrow0 = qb * 64 + wave * 16;
    const int qg    = qrow0 + l16;       // this lane's q column

    const float SL = SCALE * LOG2E;
    bf16x8 aq[4];
    {
        const float* qsrc = Qp + (size_t)(qrow0 + l16) * QKVN + h * DH + quad * 8;
#pragma unroll
        for (int c = 0; c < 4; ++c) {
            float4 f0 = *(const float4*)(qsrc + c * 32);
            float4 f1 = *(const float4*)(qsrc + c * 32 + 4);
            bf16x8 a;
            a[0] = f2bf(f0.x * SL); a[1] = f2bf(f0.y * SL);
            a[2] = f2bf(f0.z * SL); a[3] = f2bf(f0.w * SL);
            a[4] = f2bf(f1.x * SL); a[5] = f2bf(f1.y * SL);
            a[6] = f2bf(f1.z * SL); a[7] = f2bf(f1.w * SL);
            aq[c] = a;
        }
    }

    f32x4 of[8];
#pragma unroll
    for (int t = 0; t < 8; ++t) of[t] = (f32x4){0.f, 0.f, 0.f, 0.f};
    float m_old = -1e30f, l_sum = 0.f;

    for (int kt = kt0; kt < kt1; ++kt) {
        const int kbase = kt * 32;
        __syncthreads();
        {
#pragma unroll
            for (int i = 0; i < 2; ++i) {
                int cid = tid + i * 256;
                int r = cid >> 4, c = (cid & 15) * 8;
                *(int4*)&Ks[r][c] =
                    *(const int4*)(Kb + (size_t)(kbase + r) * (NKV * DH) + kvh * DH + c);
            }
        }
        {
#pragma unroll
            for (int i = 0; i < 2; ++i) {
                int cid = tid + i * 256;
                int d = cid >> 2, c = (cid & 3) * 8;
                *(int4*)&Vs[d][c] =
                    *(const int4*)(Vtb + (size_t)kvh * DH * SEQ + (size_t)d * SEQ + kbase + c);
            }
        }
        __syncthreads();

        if (kbase > qrow0 + 15) continue;   // wave-uniform fully-masked tile

        f32x4 s0 = (f32x4){0.f, 0.f, 0.f, 0.f};
        f32x4 s1 = (f32x4){0.f, 0.f, 0.f, 0.f};
#pragma unroll
        for (int c = 0; c < 4; ++c) {
            bf16x8 ak0 = *(const bf16x8*)&Ks[l16][c * 32 + quad * 8];
            bf16x8 ak1 = *(const bf16x8*)&Ks[16 + l16][c * 32 + quad * 8];
            s0 = __builtin_amdgcn_mfma_f32_16x16x32_bf16(ak0, aq[c], s0, 0, 0, 0);
            s1 = __builtin_amdgcn_mfma_f32_16x16x32_bf16(ak1, aq[c], s1, 0, 0, 0);
        }

        float x[8];
#pragma unroll
        for (int r = 0; r < 4; ++r) {
            x[r]     = (kbase + quad * 4 + r      <= qg) ? s0[r] : -1e30f;
            x[4 + r] = (kbase + 16 + quad * 4 + r <= qg) ? s1[r] : -1e30f;
        }
        float mr = x[0];
#pragma unroll
        for (int i = 1; i < 8; ++i) mr = fmaxf(mr, x[i]);
        mr = fmaxf(mr, __shfl_xor(mr, 16));
        mr = fmaxf(mr, __shfl_xor(mr, 32));
        float mn    = fmaxf(m_old, mr);
        float alpha = __builtin_amdgcn_exp2f(m_old - mn);
        float p[8], ps = 0.f;
#pragma unroll
        for (int i = 0; i < 8; ++i) { p[i] = __builtin_amdgcn_exp2f(x[i] - mn); ps += p[i]; }
        ps += __shfl_xor(ps, 16);
        ps += __shfl_xor(ps, 32);
        l_sum = l_sum * alpha + ps;

        bf16x4 w0 = { f2bf(p[0]), f2bf(p[1]), f2bf(p[2]), f2bf(p[3]) };
        bf16x4 w1 = { f2bf(p[4]), f2bf(p[5]), f2bf(p[6]), f2bf(p[7]) };
        *(bf16x4*)&Ps[wave][l16][quad * 4]      = w0;
        *(bf16x4*)&Ps[wave][l16][16 + quad * 4] = w1;

        if (__ballot(mn > m_old)) {
#pragma unroll
            for (int t = 0; t < 8; ++t)
#pragma unroll
                for (int r = 0; r < 4; ++r) of[t][r] *= alpha;
        }
        m_old = mn;

        bf16x8 bp = *(const bf16x8*)&Ps[wave][l16][quad * 8];
#pragma unroll
        for (int t = 0; t < 8; ++t) {
            bf16x8 av = *(const bf16x8*)&Vs[t * 16 + l16][quad * 8];
            of[t] = __builtin_amdgcn_mfma_f32_16x16x32_bf16(av, bp, of[t], 0, 0, 0);
        }
    }

    float inv = 1.f / l_sum;
    if (slot < 0) {
        short* dst = ctx + (size_t)qg * HID + h * DH + quad * 4;
#pragma unroll
        for (int t = 0; t < 8; ++t) {
            bf16x4 wv = { f2bf(of[t][0] * inv), f2bf(of[t][1] * inv),
                          f2bf(of[t][2] * inv), f2bf(of[t][3] * inv) };
            *(bf16x4*)(dst + t * 16) = wv;
        }
    } else {
        int qlocal = wave * 16 + l16;
        short* dst = opart + (size_t)slot * 8192 + qlocal * 128 + quad * 4;
#pragma unroll
        for (int t = 0; t < 8; ++t) {
            bf16x4 wv = { f2bf(of[t][0] * inv), f2bf(of[t][1] * inv),
                          f2bf(of[t][2] * inv), f2bf(of[t][3] * inv) };
            *(bf16x4*)(dst + t * 16) = wv;
        }
        if (quad == 0) mlbuf[slot * 64 + qlocal] = make_float2(m_old, l_sum);
    }
}

// ---------------------------------------------------------------------------
// Merge two key-chunk partials per (qb>=16, h) into ctx.
// ---------------------------------------------------------------------------
__global__ void attn_merge(const short* __restrict__ opart,
                           const float2* __restrict__ mlbuf,
                           short* __restrict__ ctx)
{
    const int qb = 16 + (blockIdx.x >> 4);
    const int h  = blockIdx.x & 15;
    const int s0 = ((qb - 16) * 16 + h) * 2;
    const int s1 = s0 + 1;
    const int t  = threadIdx.x;
    const int r  = t >> 2;            // q-row local 0..63
    const int c0 = (t & 3) * 32;      // 32 d-cols

    float2 a = mlbuf[s0 * 64 + r];
    float2 b = mlbuf[s1 * 64 + r];
    float mm = fmaxf(a.x, b.x);
    float w0 = __builtin_amdgcn_exp2f(a.x - mm) * a.y;
    float w1 = __builtin_amdgcn_exp2f(b.x - mm) * b.y;
    float inv = 1.f / (w0 + w1);
    w0 *= inv; w1 *= inv;

    const short* p0 = opart + (size_t)s0 * 8192 + r * 128 + c0;
    const short* p1 = opart + (size_t)s1 * 8192 + r * 128 + c0;
    short* dst = ctx + (size_t)(qb * 64 + r) * HID + h * DH + c0;
#pragma unroll
    for (int i = 0; i < 8; ++i) {
        bf16x4 v0 = *(const bf16x4*)(p0 + i * 4);
        bf16x4 v1 = *(const bf16x4*)(p1 + i * 4);
        bf16x4 o;
#pragma unroll
        for (int j = 0; j < 4; ++j)
            o[j] = f2bf(w0 * bf2f(v0[j]) + w1 * bf2f(v1[j]));
        *(bf16x4*)(dst + i * 4) = o;
    }
}

// ---------------------------------------------------------------------------
extern "C" void kernel_launch(void* const* d_in, const int* in_sizes, int n_in,
                              void* d_out, int out_size, void* d_ws, size_t ws_size,
                              hipStream_t stream)
{
    const float* hs   = (const float*)d_in[0];
    const float* cosp = (const float*)d_in[1];
    const float* sinp = (const float*)d_in[2];
    const float* Wq = (const float*)d_in[4];
    const float* bq = (const float*)d_in[5];
    const float* Wk = (const float*)d_in[6];
    const float* bk = (const float*)d_in[7];
    const float* Wv = (const float*)d_in[8];
    const float* bv = (const float*)d_in[9];
    const float* Wo = (const float*)d_in[10];
    float* out = (float*)d_out;

    char* w = (char*)d_ws;
    short*  btq   = (short*)w;   w += (size_t)QKVN * HID * 2;          // 10 MB
    short*  wot   = (short*)w;   w += (size_t)HID * HID * 2;           //  8 MB
    float*  qkv   = (float*)w;   w += (size_t)SEQ * QKVN * 4;          // 20 MB
    short*  kbf   = (short*)w;   w += (size_t)SEQ * (NKV * DH) * 2;    //  1 MB
    short*  vtb   = (short*)w;   w += (size_t)NKV * DH * SEQ * 2;      //  1 MB
    short*  ctxb  = (short*)w;   w += (size_t)SEQ * HID * 2;           //  8 MB
    short*  opart = (short*)w;   w += (size_t)512 * 8192 * 2;          //  8 MB
    float2* mlbuf = (float2*)w;                                        // 256 KB

    // 0. zero the split-K accumulation targets
    hipMemsetAsync(qkv, 0, (size_t)SEQ * QKVN * 4, stream);
    hipMemsetAsync(out, 0, (size_t)SEQ * HID * 4, stream);

    // 1. all weight transposes (fp32 [K][N] -> bf16 [N][K])
    transp_all<<<9216, 256, 0, stream>>>(Wq, Wk, Wv, Wo, btq, wot);

    // 2. QKV projection, split-K=2, atomic accumulate (bias deferred)
    gemm_qkv<<<dim3(QKVN / 128, SEQ / 128, 2), 256, 0, stream>>>(hs, btq, qkv);

    // 3. bias + RoPE Q/K + V transpose, one launch
    {
        int total = SEQ * NH * 64 + SEQ * NKV * 64 + NKV * DH * SEQ;
        rope_cvt<<<total / 256, 256, 0, stream>>>(qkv, cosp, sinp, bq, bk, bv, kbf, vtb);
    }

    // 4. attention: key-split for qb>=16, then merge
    attn_mfma<<<768, 256, 0, stream>>>(qkv, kbf, vtb, ctxb, opart, mlbuf);
    attn_merge<<<256, 256, 0, stream>>>(opart, mlbuf, ctxb);

    // 5. output projection, split-K=2, atomic accumulate into zeroed out
    gemm_wo<<<dim3(HID / 128, SEQ / 128, 2), 256, 0, stream>>>(ctxb, wot, out);
}